// Round 3
// baseline (311.237 us; speedup 1.0000x reference)
//
#include <hip/hip_runtime.h>
#include <hip/hip_bf16.h>
#include <stdint.h>

// Problem constants (B,S,I fixed by setup_inputs)
#define B_DIM 8
#define S_DIM 4096
#define I_DIM 256
#define M_DIM (B_DIM * S_DIM)   // 32768 rows
#define N_DIM 1536              // 6*OUT gate columns
#define K_DIM 512               // WINDOW*I

// GEMM tiling
#define TM 128
#define TN 128
#define BK 64

typedef __attribute__((ext_vector_type(8))) short bf16x8;   // 8 bf16 in 4 VGPRs
typedef __attribute__((ext_vector_type(4))) float f32x4;
typedef _Float16 h4 __attribute__((ext_vector_type(4)));
typedef _Float16 h8 __attribute__((ext_vector_type(8)));

typedef const void __attribute__((address_space(1)))* gas_ptr;
typedef void __attribute__((address_space(3)))* las_ptr;

__device__ __forceinline__ void gload_lds16(const void* g, void* l) {
    // async global->LDS, 16B/lane; LDS dest = wave-uniform base + lane*16
    __builtin_amdgcn_global_load_lds((gas_ptr)(uintptr_t)g, (las_ptr)(uintptr_t)l, 16, 0, 0);
}

__device__ __forceinline__ float fast_sigmoid(float x) {
    return 1.0f / (1.0f + __expf(-x));   // exp(+inf) -> 1/inf = 0, safe
}
__device__ __forceinline__ float fast_tanh(float x) {
    float ax = fabsf(x);
    float e = __expf(-2.0f * ax);        // arg <= 0, never overflows
    float t = (1.0f - e) / (1.0f + e);
    return copysignf(t, x);
}

__device__ __forceinline__ unsigned short f2bf(float f) {
    uint32_t u = __float_as_uint(f);
    uint32_t r = (u + 0x7FFFu + ((u >> 16) & 1u)) >> 16;
    return (unsigned short)r;
}

// ---------------------------------------------------------------------------
// fp32 -> bf16 conversion (4 elems/thread); also zero-inits the zero page
// ---------------------------------------------------------------------------
__global__ __launch_bounds__(256)
void cvt_f32_bf16(const float* __restrict__ in, unsigned short* __restrict__ out,
                  int n4, unsigned short* __restrict__ zp)
{
    int i = blockIdx.x * 256 + threadIdx.x;
    if (zp && blockIdx.x == 0 && threadIdx.x < 64) zp[threadIdx.x] = 0;
    if (i < n4) {
        float4 v = ((const float4*)in)[i];
        ushort4 o;
        o.x = f2bf(v.x); o.y = f2bf(v.y); o.z = f2bf(v.z); o.w = f2bf(v.w);
        ((ushort4*)out)[i] = o;
    }
}

// ---------------------------------------------------------------------------
// Kernel 1: windowed GEMM + bias, PRE-ACTIVATION fp16 output, TRANSPOSED:
//   gT[col][m], col = gate*512 + dir*256 + oo, m = b*4096 + s
// Activations (tanh/sigmoid) are applied in the scan kernels (memory-bound
// there -> VALU is free; here they doubled the kernel: MfmaUtil was 20%).
// A[m][k] = (k<256) ? x[b, s-1, k] (0 if s==0) : x[b, s, k-256]
// ---------------------------------------------------------------------------
__global__ __launch_bounds__(256, 2)
void qrnn_gemm(const __hip_bfloat16* __restrict__ x,
               const __hip_bfloat16* __restrict__ W,
               const float* __restrict__ bias,
               _Float16* __restrict__ gT,
               const __hip_bfloat16* __restrict__ zeroPage)
{
    __shared__ __hip_bfloat16 lA[TM * BK];   // 16 KB, XOR-8 swizzled chunks of 8
    __shared__ __hip_bfloat16 lB[TN * BK];   // 16 KB

    const int tid = threadIdx.x;
    const int w = tid >> 6;        // wave 0..3
    const int l = tid & 63;        // lane

    const int tileM = blockIdx.x & 255;   // 256 M-tiles
    const int tileN = blockIdx.x >> 8;    // 12 N-tiles
    const int m0 = tileM * TM;
    const int n0 = tileN * TN;
    const int bIdx = m0 >> 12;            // batch (tiles never straddle b)
    const int sBase = m0 & 4095;

    // staging: lane l fills LDS slot (row rowInP, chunk slot l&7) holding
    // global chunk (l&7) ^ (row&7)  [XOR-8 swizzle; wave-uniform-base rule]
    const int c8 = (l & 7) ^ ((l >> 3) & 7);
    const int rowInP = w * 8 + (l >> 3);

    const int la = l & 15, lq = l >> 4;
    const int wm = w >> 1, wn = w & 1;

    f32x4 acc[4][4] = {};

    for (int kt = 0; kt < K_DIM / BK; ++kt) {
        __syncthreads();
        const int kcol = kt * 64 + c8 * 8;
#pragma unroll
        for (int p = 0; p < 4; ++p) {
            const int r = p * 32 + rowInP;
            const int srow = sBase + r;
            const __hip_bfloat16* srcA;
            if (kcol < 256) {
                srcA = (srow == 0) ? zeroPage
                     : x + ((size_t)((bIdx << 12) + srow - 1) * 256 + kcol);
            } else {
                srcA = x + ((size_t)((bIdx << 12) + srow) * 256 + (kcol - 256));
            }
            gload_lds16(srcA, &lA[p * 2048 + w * 512]);
            const int nrow = n0 + r;
            gload_lds16(W + ((size_t)nrow * 512 + kcol), &lB[p * 2048 + w * 512]);
        }
        __syncthreads();

#pragma unroll
        for (int kk = 0; kk < 2; ++kk) {
            bf16x8 af[4], bfr[4];
#pragma unroll
            for (int i = 0; i < 4; ++i) {
                const int ra = wm * 64 + i * 16 + la;
                const int ch = (kk * 4 + lq) ^ (ra & 7);
                af[i] = *(const bf16x8*)&lA[ra * 64 + ch * 8];
            }
#pragma unroll
            for (int j = 0; j < 4; ++j) {
                const int rb = wn * 64 + j * 16 + la;
                const int ch = (kk * 4 + lq) ^ (rb & 7);
                bfr[j] = *(const bf16x8*)&lB[rb * 64 + ch * 8];
            }
#pragma unroll
            for (int i = 0; i < 4; ++i)
#pragma unroll
                for (int j = 0; j < 4; ++j)
                    acc[i][j] = __builtin_amdgcn_mfma_f32_16x16x32_bf16(
                        af[i], bfr[j], acc[i][j], 0, 0, 0);
        }
    }

    // Thin epilogue: bias + fp16 cvt + one 8B store per (i,j).
    // C/D layout: col=lane&15, row=(lane>>4)*4+reg -> the 4 regs are 4
    // CONSECUTIVE m-rows => contiguous in gT[col][m]. 16 dwordx2 stores.
#pragma unroll
    for (int j = 0; j < 4; ++j) {
        const int col = n0 + wn * 64 + j * 16 + la;
        const float bv = bias[col];
        _Float16* dst = gT + (size_t)col * 32768 + m0 + wm * 64 + lq * 4;
#pragma unroll
        for (int i = 0; i < 4; ++i) {
            h4 hv;
#pragma unroll
            for (int rr = 0; rr < 4; ++rr)
                hv[rr] = (_Float16)(acc[i][j][rr] + bv);
            *(h4*)(dst + i * 16) = hv;
        }
    }
}

// ---------------------------------------------------------------------------
// Chunked linear-recurrence scan: c[t] = f*c + (1-f)*z (fwd dir=0, bwd dir=1)
// gT[col][m] pre-activation fp16; activations applied here (VALU hidden
// under the memory-bound stream). Per thread: one sequence chunk of 64 t,
// contiguous in memory -> half8 (16B) vector loads.
// ---------------------------------------------------------------------------
#define NCHUNK 64
#define CLEN 64
#define NSEQ 4096

__global__ __launch_bounds__(256)
void qrnn_scanA(const _Float16* __restrict__ gT,
                float* __restrict__ cA, float* __restrict__ cB)
{
    const int oo = threadIdx.x;
    const int bid = blockIdx.x;           // b*128 + dir*64 + chunk
    const int chunk = bid & 63;
    const int dir = (bid >> 6) & 1;
    const int b = bid >> 7;

    const size_t base = (size_t)(dir * 256 + oo) * 32768 + (b << 12) + chunk * CLEN;
    const h8* zp = (const h8*)(gT + base);
    const h8* fp = (const h8*)(gT + ((size_t)512 * 32768) + base);

    float A = 1.0f, Bv = 0.0f;
    if (dir == 0) {
#pragma unroll
        for (int v = 0; v < 8; ++v) {
            h8 zv = zp[v], fv = fp[v];
#pragma unroll
            for (int e = 0; e < 8; ++e) {
                float f = fast_sigmoid((float)fv[e]);
                float z = fast_tanh((float)zv[e]);
                Bv = f * Bv + (1.0f - f) * z;
                A *= f;
            }
        }
    } else {
#pragma unroll
        for (int v = 7; v >= 0; --v) {
            h8 zv = zp[v], fv = fp[v];
#pragma unroll
            for (int e = 7; e >= 0; --e) {
                float f = fast_sigmoid((float)fv[e]);
                float z = fast_tanh((float)zv[e]);
                Bv = f * Bv + (1.0f - f) * z;
                A *= f;
            }
        }
    }
    const int seq = (b * 2 + dir) * 256 + oo;
    cA[chunk * NSEQ + seq] = A;
    cB[chunk * NSEQ + seq] = Bv;
}

__global__ __launch_bounds__(256)
void qrnn_scanB(const float* __restrict__ cA, const float* __restrict__ cB,
                float* __restrict__ carry)
{
    const int seq = blockIdx.x * 256 + threadIdx.x;   // 16 blocks
    const int dir = (seq >> 8) & 1;
    float c = 0.0f;
    if (dir == 0) {
#pragma unroll 4
        for (int ch = 0; ch < NCHUNK; ++ch) {
            carry[ch * NSEQ + seq] = c;
            c = cA[ch * NSEQ + seq] * c + cB[ch * NSEQ + seq];
        }
    } else {
#pragma unroll 4
        for (int ch = NCHUNK - 1; ch >= 0; --ch) {
            carry[ch * NSEQ + seq] = c;
            c = cA[ch * NSEQ + seq] * c + cB[ch * NSEQ + seq];
        }
    }
}

__global__ __launch_bounds__(256)
void qrnn_scanC(const _Float16* __restrict__ gT,
                const float* __restrict__ carry,
                float* __restrict__ out)
{
    const int oo = threadIdx.x;
    const int bid = blockIdx.x;
    const int chunk = bid & 63;
    const int dir = (bid >> 6) & 1;
    const int b = bid >> 7;
    const int zc = dir * 256 + oo;
    const int seq = (b * 2 + dir) * 256 + oo;
    const int t0 = chunk * CLEN;

    const size_t base = (size_t)zc * 32768 + (b << 12) + t0;
    const h8* zp = (const h8*)(gT + base);
    const h8* fp = (const h8*)(gT + ((size_t)512 * 32768) + base);
    const h8* op = (const h8*)(gT + ((size_t)1024 * 32768) + base);

    float c = carry[chunk * NSEQ + seq];
    if (dir == 0) {
#pragma unroll
        for (int v = 0; v < 8; ++v) {
            h8 zv = zp[v], fv = fp[v], ov = op[v];
#pragma unroll
            for (int e = 0; e < 8; ++e) {
                float f = fast_sigmoid((float)fv[e]);
                float z = fast_tanh((float)zv[e]);
                float o = fast_sigmoid((float)ov[e]);
                c = f * c + (1.0f - f) * z;
                const int t = t0 + v * 8 + e;
                out[((size_t)((b << 12) + t)) * 512 + zc] = o * c;
            }
        }
    } else {
#pragma unroll
        for (int v = 7; v >= 0; --v) {
            h8 zv = zp[v], fv = fp[v], ov = op[v];
#pragma unroll
            for (int e = 7; e >= 0; --e) {
                float f = fast_sigmoid((float)fv[e]);
                float z = fast_tanh((float)zv[e]);
                float o = fast_sigmoid((float)ov[e]);
                c = f * c + (1.0f - f) * z;
                const int t = t0 + v * 8 + e;
                out[((size_t)((b << 12) + t)) * 512 + zc] = o * c;
            }
        }
    }
}

// ---------------------------------------------------------------------------
extern "C" void kernel_launch(void* const* d_in, const int* in_sizes, int n_in,
                              void* d_out, int out_size, void* d_ws, size_t ws_size,
                              hipStream_t stream)
{
    const float* x    = (const float*)d_in[0];   // (8,4096,256) fp32
    const float* W    = (const float*)d_in[1];   // (1536,512)  fp32
    const float* bias = (const float*)d_in[2];   // (1536,)     fp32
    float* out = (float*)d_out;                  // (8,4096,512) fp32

    char* ws = (char*)d_ws;
    size_t off = 0;
    __hip_bfloat16* xb = (__hip_bfloat16*)(ws + off); off += (size_t)M_DIM * I_DIM * 2;   // 16.8 MB
    __hip_bfloat16* Wb = (__hip_bfloat16*)(ws + off); off += (size_t)N_DIM * K_DIM * 2;   // 1.5 MB
    _Float16* gT = (_Float16*)(ws + off); off += (size_t)N_DIM * M_DIM * 2;               // 100.7 MB
    float* cA    = (float*)(ws + off); off += (size_t)NSEQ * NCHUNK * 4;
    float* cB    = (float*)(ws + off); off += (size_t)NSEQ * NCHUNK * 4;
    float* carry = (float*)(ws + off); off += (size_t)NSEQ * NCHUNK * 4;
    unsigned short* zeroPage = (unsigned short*)(ws + off); off += 128;

    const int nx4 = (M_DIM * I_DIM) / 4;
    const int nw4 = (N_DIM * K_DIM) / 4;
    cvt_f32_bf16<<<dim3((nx4 + 255) / 256), dim3(256), 0, stream>>>(x, (unsigned short*)xb, nx4, zeroPage);
    cvt_f32_bf16<<<dim3((nw4 + 255) / 256), dim3(256), 0, stream>>>(W, (unsigned short*)Wb, nw4, nullptr);

    qrnn_gemm<<<dim3(256 * 12), dim3(256), 0, stream>>>(xb, Wb, bias, gT,
                                                        (const __hip_bfloat16*)zeroPage);
    qrnn_scanA<<<dim3(B_DIM * 2 * NCHUNK), dim3(256), 0, stream>>>(gT, cA, cB);
    qrnn_scanB<<<dim3(NSEQ / 256), dim3(256), 0, stream>>>(cA, cB, carry);
    qrnn_scanC<<<dim3(B_DIM * 2 * NCHUNK), dim3(256), 0, stream>>>(gT, carry, out);
}

// Round 4
// 224.728 us; speedup vs baseline: 1.3850x; 1.3850x over previous
//
#include <hip/hip_runtime.h>
#include <hip/hip_bf16.h>
#include <stdint.h>

// Problem constants
#define B_DIM 8
#define S_DIM 4096
#define I_DIM 256
#define M_DIM (B_DIM * S_DIM)   // 32768 rows
#define N_DIM 1536              // 6*OUT gate columns
#define K_DIM 512               // WINDOW*I

// GEMM tiling
#define TM 128
#define TN 128
#define BK 64

// scan decomposition
#define NCHUNK 128
#define CLEN 32
#define NSEQ 4096

typedef __attribute__((ext_vector_type(8))) short bf16x8;
typedef __attribute__((ext_vector_type(4))) float f32x4;
typedef _Float16 h4 __attribute__((ext_vector_type(4)));

typedef const void __attribute__((address_space(1)))* gas_ptr;
typedef void __attribute__((address_space(3)))* las_ptr;

__device__ __forceinline__ void gload_lds16(const void* g, void* l) {
    __builtin_amdgcn_global_load_lds((gas_ptr)(uintptr_t)g, (las_ptr)(uintptr_t)l, 16, 0, 0);
}

__device__ __forceinline__ float fast_sigmoid(float x) {
    return 1.0f / (1.0f + __expf(-x));
}
__device__ __forceinline__ float fast_tanh(float x) {
    float ax = fabsf(x);
    float e = __expf(-2.0f * ax);
    float t = (1.0f - e) / (1.0f + e);
    return copysignf(t, x);
}

__device__ __forceinline__ unsigned short f2bf(float f) {
    uint32_t u = __float_as_uint(f);
    uint32_t r = (u + 0x7FFFu + ((u >> 16) & 1u)) >> 16;
    return (unsigned short)r;
}

// ---------------------------------------------------------------------------
// fp32 -> bf16 conversion; also zero-inits the zero page
// ---------------------------------------------------------------------------
__global__ __launch_bounds__(256)
void cvt_f32_bf16(const float* __restrict__ in, unsigned short* __restrict__ out,
                  int n4, unsigned short* __restrict__ zp)
{
    int i = blockIdx.x * 256 + threadIdx.x;
    if (zp && blockIdx.x == 0 && threadIdx.x < 64) zp[threadIdx.x] = 0;
    if (i < n4) {
        float4 v = ((const float4*)in)[i];
        ushort4 o;
        o.x = f2bf(v.x); o.y = f2bf(v.y); o.z = f2bf(v.z); o.w = f2bf(v.w);
        ((ushort4*)out)[i] = o;
    }
}

// ---------------------------------------------------------------------------
// Windowed GEMM + bias -> PRE-ACTIVATION fp16, layout gact[m][col] (row-major,
// col contiguous: scans keep inter-lane contiguity -> no fetch amplification).
// B-COLUMN PERMUTATION: LDS B row (j*16+la within a 64-group) holds W row
// (la*4+j), so lane la's four j-fragments are 4 CONSECUTIVE output columns
// -> epilogue is 16 x 8B stores instead of 64 x 2B.
// A[m][k] = (k<256) ? x[b, s-1, k] (0 if s==0) : x[b, s, k-256]
// ---------------------------------------------------------------------------
__global__ __launch_bounds__(256, 2)
void qrnn_gemm(const __hip_bfloat16* __restrict__ x,
               const __hip_bfloat16* __restrict__ W,
               const float* __restrict__ bias,
               _Float16* __restrict__ gact,
               const __hip_bfloat16* __restrict__ zeroPage)
{
    __shared__ __hip_bfloat16 lA[TM * BK];   // 16 KB, XOR-8 swizzled chunks of 8
    __shared__ __hip_bfloat16 lB[TN * BK];   // 16 KB

    const int tid = threadIdx.x;
    const int w = tid >> 6;
    const int l = tid & 63;

    const int tileM = blockIdx.x & 255;   // 256 M-tiles (fast-varying: W reuse)
    const int tileN = blockIdx.x >> 8;    // 12 N-tiles
    const int m0 = tileM * TM;
    const int n0 = tileN * TN;
    const int bIdx = m0 >> 12;
    const int sBase = m0 & 4095;

    const int c8 = (l & 7) ^ ((l >> 3) & 7);
    const int rowInP = w * 8 + (l >> 3);

    const int la = l & 15, lq = l >> 4;
    const int wm = w >> 1, wn = w & 1;

    f32x4 acc[4][4] = {};

    for (int kt = 0; kt < K_DIM / BK; ++kt) {
        __syncthreads();
        const int kcol = kt * 64 + c8 * 8;
#pragma unroll
        for (int p = 0; p < 4; ++p) {
            const int r = p * 32 + rowInP;
            // A tile: windowed x
            const int srow = sBase + r;
            const __hip_bfloat16* srcA;
            if (kcol < 256) {
                srcA = (srow == 0) ? zeroPage
                     : x + ((size_t)((bIdx << 12) + srow - 1) * 256 + kcol);
            } else {
                srcA = x + ((size_t)((bIdx << 12) + srow) * 256 + (kcol - 256));
            }
            gload_lds16(srcA, &lA[p * 2048 + w * 512]);
            // B tile: permuted W row (4x16 transpose within each 64-group)
            const int nr = (r & 64) + ((r & 15) << 2) + ((r >> 4) & 3);
            gload_lds16(W + ((size_t)(n0 + nr) * 512 + kcol), &lB[p * 2048 + w * 512]);
        }
        __syncthreads();

#pragma unroll
        for (int kk = 0; kk < 2; ++kk) {
            bf16x8 af[4], bfr[4];
#pragma unroll
            for (int i = 0; i < 4; ++i) {
                const int ra = wm * 64 + i * 16 + la;
                const int ch = (kk * 4 + lq) ^ (ra & 7);
                af[i] = *(const bf16x8*)&lA[ra * 64 + ch * 8];
            }
#pragma unroll
            for (int j = 0; j < 4; ++j) {
                const int rb = wn * 64 + j * 16 + la;
                const int ch = (kk * 4 + lq) ^ (rb & 7);
                bfr[j] = *(const bf16x8*)&lB[rb * 64 + ch * 8];
            }
#pragma unroll
            for (int i = 0; i < 4; ++i)
#pragma unroll
                for (int j = 0; j < 4; ++j)
                    acc[i][j] = __builtin_amdgcn_mfma_f32_16x16x32_bf16(
                        af[i], bfr[j], acc[i][j], 0, 0, 0);
        }
    }

    // Thin epilogue: lane la's j=0..3 are global cols colBase..colBase+3.
    // Per (i,rr): one h4 (8B) store; wave = 4 x 128B contiguous segments.
    const int colBase = n0 + wn * 64 + la * 4;
    const float4 bv4 = *(const float4*)(bias + colBase);
#pragma unroll
    for (int i = 0; i < 4; ++i) {
        const int row0 = m0 + wm * 64 + i * 16 + lq * 4;
#pragma unroll
        for (int rr = 0; rr < 4; ++rr) {
            h4 hv;
            hv[0] = (_Float16)(acc[i][0][rr] + bv4.x);
            hv[1] = (_Float16)(acc[i][1][rr] + bv4.y);
            hv[2] = (_Float16)(acc[i][2][rr] + bv4.z);
            hv[3] = (_Float16)(acc[i][3][rr] + bv4.w);
            *(h4*)(gact + (size_t)(row0 + rr) * N_DIM + colBase) = hv;
        }
    }
}

// ---------------------------------------------------------------------------
// Scans over gact[m][col] (pre-activation fp16). 4 channels/thread (h4),
// lanes contiguous across channels -> coalesced. Activations applied here
// (memory-bound kernels; VALU+transcendentals hide under HBM).
// block = 256 threads = 64 channel-quads x 4 chunk slots.
// grid  = b(8) x dir(2) x chunkgroups(32) = 512 blocks.
// ---------------------------------------------------------------------------
__global__ __launch_bounds__(256)
void qrnn_scanA(const _Float16* __restrict__ gact,
                float* __restrict__ cA, float* __restrict__ cB)
{
    const int c4  = threadIdx.x & 63;
    const int chs = threadIdx.x >> 6;
    const int cp  = blockIdx.x & 31;
    const int dir = (blockIdx.x >> 5) & 1;
    const int b   = blockIdx.x >> 6;
    const int chunk = cp * 4 + chs;
    const int zc = dir * 256 + c4 * 4;
    const int t0 = chunk * CLEN;

    float A[4] = {1.f, 1.f, 1.f, 1.f};
    float Bv[4] = {0.f, 0.f, 0.f, 0.f};
#pragma unroll 8
    for (int tt = 0; tt < CLEN; ++tt) {
        const int t = dir ? (t0 + CLEN - 1 - tt) : (t0 + tt);
        const _Float16* rowp = gact + (size_t)((b << 12) + t) * N_DIM + zc;
        h4 zv = *(const h4*)(rowp);         // z gate: cols [0,512)
        h4 fv = *(const h4*)(rowp + 512);   // f gate: cols [512,1024)
#pragma unroll
        for (int e = 0; e < 4; ++e) {
            float f = fast_sigmoid((float)fv[e]);
            float z = fast_tanh((float)zv[e]);
            Bv[e] = f * Bv[e] + (1.0f - f) * z;
            A[e] *= f;
        }
    }
    const int seq0 = (b * 2 + dir) * 256 + c4 * 4;
    *(float4*)(cA + (size_t)chunk * NSEQ + seq0) = make_float4(A[0], A[1], A[2], A[3]);
    *(float4*)(cB + (size_t)chunk * NSEQ + seq0) = make_float4(Bv[0], Bv[1], Bv[2], Bv[3]);
}

__global__ __launch_bounds__(256)
void qrnn_scanB(const float* __restrict__ cA, const float* __restrict__ cB,
                float* __restrict__ carry)
{
    const int seq = blockIdx.x * 256 + threadIdx.x;   // 16 blocks
    const int dir = (seq >> 8) & 1;
    float c = 0.0f;
    if (dir == 0) {
#pragma unroll 4
        for (int ch = 0; ch < NCHUNK; ++ch) {
            carry[ch * NSEQ + seq] = c;
            c = cA[ch * NSEQ + seq] * c + cB[ch * NSEQ + seq];
        }
    } else {
#pragma unroll 4
        for (int ch = NCHUNK - 1; ch >= 0; --ch) {
            carry[ch * NSEQ + seq] = c;
            c = cA[ch * NSEQ + seq] * c + cB[ch * NSEQ + seq];
        }
    }
}

__global__ __launch_bounds__(256)
void qrnn_scanC(const _Float16* __restrict__ gact,
                const float* __restrict__ carry,
                float* __restrict__ out)
{
    const int c4  = threadIdx.x & 63;
    const int chs = threadIdx.x >> 6;
    const int cp  = blockIdx.x & 31;
    const int dir = (blockIdx.x >> 5) & 1;
    const int b   = blockIdx.x >> 6;
    const int chunk = cp * 4 + chs;
    const int zc = dir * 256 + c4 * 4;
    const int t0 = chunk * CLEN;
    const int seq0 = (b * 2 + dir) * 256 + c4 * 4;

    float4 cv = *(const float4*)(carry + (size_t)chunk * NSEQ + seq0);
    float c[4] = {cv.x, cv.y, cv.z, cv.w};
#pragma unroll 8
    for (int tt = 0; tt < CLEN; ++tt) {
        const int t = dir ? (t0 + CLEN - 1 - tt) : (t0 + tt);
        const size_t row = (size_t)((b << 12) + t);
        const _Float16* rowp = gact + row * N_DIM + zc;
        h4 zv = *(const h4*)(rowp);
        h4 fv = *(const h4*)(rowp + 512);
        h4 ov = *(const h4*)(rowp + 1024);
        float4 res;
        float* rp = &res.x;
#pragma unroll
        for (int e = 0; e < 4; ++e) {
            float f = fast_sigmoid((float)fv[e]);
            float z = fast_tanh((float)zv[e]);
            float o = fast_sigmoid((float)ov[e]);
            c[e] = f * c[e] + (1.0f - f) * z;
            rp[e] = o * c[e];
        }
        *(float4*)(out + row * 512 + zc) = res;
    }
}

// ---------------------------------------------------------------------------
extern "C" void kernel_launch(void* const* d_in, const int* in_sizes, int n_in,
                              void* d_out, int out_size, void* d_ws, size_t ws_size,
                              hipStream_t stream)
{
    const float* x    = (const float*)d_in[0];   // (8,4096,256) fp32
    const float* W    = (const float*)d_in[1];   // (1536,512)  fp32
    const float* bias = (const float*)d_in[2];   // (1536,)     fp32
    float* out = (float*)d_out;                  // (8,4096,512) fp32

    char* ws = (char*)d_ws;
    size_t off = 0;
    __hip_bfloat16* xb = (__hip_bfloat16*)(ws + off); off += (size_t)M_DIM * I_DIM * 2;   // 16.8 MB
    __hip_bfloat16* Wb = (__hip_bfloat16*)(ws + off); off += (size_t)N_DIM * K_DIM * 2;   // 1.5 MB
    _Float16* gact = (_Float16*)(ws + off); off += (size_t)M_DIM * N_DIM * 2;             // 100.7 MB
    float* cA    = (float*)(ws + off); off += (size_t)NSEQ * NCHUNK * 4;   // 2 MB
    float* cB    = (float*)(ws + off); off += (size_t)NSEQ * NCHUNK * 4;   // 2 MB
    float* carry = (float*)(ws + off); off += (size_t)NSEQ * NCHUNK * 4;   // 2 MB
    unsigned short* zeroPage = (unsigned short*)(ws + off); off += 128;

    const int nx4 = (M_DIM * I_DIM) / 4;
    const int nw4 = (N_DIM * K_DIM) / 4;
    cvt_f32_bf16<<<dim3((nx4 + 255) / 256), dim3(256), 0, stream>>>(x, (unsigned short*)xb, nx4, zeroPage);
    cvt_f32_bf16<<<dim3((nw4 + 255) / 256), dim3(256), 0, stream>>>(W, (unsigned short*)Wb, nw4, nullptr);

    qrnn_gemm<<<dim3(256 * 12), dim3(256), 0, stream>>>(xb, Wb, bias, gact,
                                                        (const __hip_bfloat16*)zeroPage);
    qrnn_scanA<<<dim3(512), dim3(256), 0, stream>>>(gact, cA, cB);
    qrnn_scanB<<<dim3(NSEQ / 256), dim3(256), 0, stream>>>(cA, cB, carry);
    qrnn_scanC<<<dim3(512), dim3(256), 0, stream>>>(gact, carry, out);
}